// Round 3
// baseline (10111.649 us; speedup 1.0000x reference)
//
#include <hip/hip_runtime.h>
#include <hip/hip_bf16.h>
#include <cstdio>

// Problem constants
#define D_MODEL 1024
#define NHEAD 8
#define DK 128
#define NLAYER 4
#define FF_DIM 4096
#define BATCH 8
#define SEQ 512
#define NTOK (BATCH * SEQ)   // 4096

typedef __attribute__((ext_vector_type(8))) short bf16x8;     // MFMA A/B frag (4 VGPR)
typedef __attribute__((ext_vector_type(4))) float f32x4;      // MFMA C/D frag
typedef __attribute__((ext_vector_type(8))) unsigned short u16x8;

__device__ __forceinline__ unsigned short f2bf(float f) {
    unsigned int u = __builtin_bit_cast(unsigned int, f);
    u += 0x7FFFu + ((u >> 16) & 1u);          // round-to-nearest-even
    return (unsigned short)(u >> 16);
}

// ---------------- block reduction helpers (256 threads) ----------------
__device__ __forceinline__ float block_reduce_sum256(float val, float* red) {
    int t = threadIdx.x;
    red[t] = val; __syncthreads();
    for (int off = 128; off > 0; off >>= 1) {
        if (t < off) red[t] += red[t + off];
        __syncthreads();
    }
    float r = red[0];
    __syncthreads();
    return r;
}

__device__ __forceinline__ float block_reduce_max256(float val, float* red) {
    int t = threadIdx.x;
    red[t] = val; __syncthreads();
    for (int off = 128; off > 0; off >>= 1) {
        if (t < off) red[t] = fmaxf(red[t], red[t + off]);
        __syncthreads();
    }
    float r = red[0];
    __syncthreads();
    return r;
}

// ---------------- embedding + positional encoding ----------------
__global__ __launch_bounds__(256) void embed_pe_kernel(
    const int* __restrict__ ids, const float* __restrict__ emb, float* __restrict__ x)
{
    int token = blockIdx.x;           // 0..4095
    int s = token & (SEQ - 1);
    int t = threadIdx.x;
    int id = ids[token];
    const float kconst = -9.210340371976184f / (float)D_MODEL; // -ln(10000)/D
    const float* erow = emb + (size_t)id * D_MODEL;
    float* xrow = x + (size_t)token * D_MODEL;
#pragma unroll
    for (int i = 0; i < 4; i++) {
        int d = t + i * 256;
        int half = d >> 1;
        float div = expf((float)(2 * half) * kconst);
        float ang = (float)s * div;
        float pe = (d & 1) ? cosf(ang) : sinf(ang);
        xrow[d] = erow[d] + pe;
    }
}

// ---------------- weight transpose + f32->bf16 convert ----------------
// W[K][N] f32  ->  Wt[N][K] bf16
__global__ __launch_bounds__(256) void transpose_bf16_kernel(
    const float* __restrict__ W, unsigned short* __restrict__ Wt, int K, int N)
{
    __shared__ unsigned short tile[32][33];
    int n0 = blockIdx.x * 32, k0 = blockIdx.y * 32;
    int t = threadIdx.x;
    int r = t >> 3, c4 = (t & 7) * 4;
    const float4 f = *(const float4*)&W[(size_t)(k0 + r) * N + n0 + c4];
    tile[r][c4 + 0] = f2bf(f.x);
    tile[r][c4 + 1] = f2bf(f.y);
    tile[r][c4 + 2] = f2bf(f.z);
    tile[r][c4 + 3] = f2bf(f.w);
    __syncthreads();
    ushort4 o;
    o.x = tile[c4 + 0][r];
    o.y = tile[c4 + 1][r];
    o.z = tile[c4 + 2][r];
    o.w = tile[c4 + 3][r];
    *(ushort4*)&Wt[(size_t)(n0 + r) * K + k0 + c4] = o;
}

// ---------------- bf16 MFMA GEMM: C[M,N] = A[M,K] @ Wt[N,K]^T + bias ----------------
// A f32 row-major, Wt bf16 [N][K] (pre-transposed weights), C f32.
// 128x128 tile, BK=32, 256 threads = 4 waves (2x2), each wave 64x64 = 4x4 frags of 16x16x32.
__global__ __launch_bounds__(256) void gemm_mfma_kernel(
    const float* __restrict__ A, const unsigned short* __restrict__ Bt,
    const float* __restrict__ bias, float* __restrict__ C,
    int M, int N, int K, int do_gelu)
{
    // fragment-order LDS: index fr = mblk*64 + kb*16 + r, 8 bf16 per fragment-row
    __shared__ __align__(16) unsigned short As[4096];   // 8 KB
    __shared__ __align__(16) unsigned short Bs[4096];   // 8 KB

    int t = threadIdx.x;
    int row0 = blockIdx.y * 128, col0 = blockIdx.x * 128;
    int wave = t >> 6, lane = t & 63;
    int wr = wave >> 1, wc = wave & 1;     // 2x2 wave grid
    int lr = lane & 15, lk = lane >> 4;    // C-frag col-in-16, row-quad

    f32x4 acc[4][4];
#pragma unroll
    for (int m = 0; m < 4; m++)
#pragma unroll
        for (int n = 0; n < 4; n++)
            acc[m][n] = (f32x4){0.f, 0.f, 0.f, 0.f};

    for (int k0 = 0; k0 < K; k0 += 32) {
        // stage A: 512 fragment-rows; thread handles sidx = t, t+256 (lane-linear LDS writes)
#pragma unroll
        for (int i = 0; i < 2; i++) {
            int sidx = t + i * 256;
            int r = sidx & 15;
            int kbm = sidx >> 4;          // 0..31
            int kb = kbm & 3;
            int mblk = kbm >> 2;          // 0..7
            int row = mblk * 16 + r;
            const float4* src = (const float4*)(A + (size_t)(row0 + row) * K + k0 + kb * 8);
            float4 f0 = src[0], f1 = src[1];
            u16x8 v;
            v[0] = f2bf(f0.x); v[1] = f2bf(f0.y); v[2] = f2bf(f0.z); v[3] = f2bf(f0.w);
            v[4] = f2bf(f1.x); v[5] = f2bf(f1.y); v[6] = f2bf(f1.z); v[7] = f2bf(f1.w);
            *(u16x8*)&As[sidx * 8] = v;
        }
        // stage B (already bf16 [N][K]): straight 16B copies
#pragma unroll
        for (int i = 0; i < 2; i++) {
            int sidx = t + i * 256;
            int r = sidx & 15;
            int kbm = sidx >> 4;
            int kb = kbm & 3;
            int nblk = kbm >> 2;
            int ncol = nblk * 16 + r;
            u16x8 v = *(const u16x8*)&Bt[(size_t)(col0 + ncol) * K + k0 + kb * 8];
            *(u16x8*)&Bs[sidx * 8] = v;
        }
        __syncthreads();

        bf16x8 a[4], b[4];
#pragma unroll
        for (int m = 0; m < 4; m++)
            a[m] = *(const bf16x8*)&As[((wr * 4 + m) * 64 + lane) * 8];
#pragma unroll
        for (int n = 0; n < 4; n++)
            b[n] = *(const bf16x8*)&Bs[((wc * 4 + n) * 64 + lane) * 8];

#pragma unroll
        for (int m = 0; m < 4; m++)
#pragma unroll
            for (int n = 0; n < 4; n++)
                acc[m][n] = __builtin_amdgcn_mfma_f32_16x16x32_bf16(a[m], b[n], acc[m][n], 0, 0, 0);
        __syncthreads();
    }

    // epilogue: C/D layout col=lane&15, row=(lane>>4)*4+reg  [m89/m91 verified]
#pragma unroll
    for (int m = 0; m < 4; m++) {
#pragma unroll
        for (int n = 0; n < 4; n++) {
            int col = col0 + wc * 64 + n * 16 + lr;
            float bv = bias[col];
#pragma unroll
            for (int i = 0; i < 4; i++) {
                int row = row0 + wr * 64 + m * 16 + lk * 4 + i;
                float v = acc[m][n][i] + bv;
                if (do_gelu) v = 0.5f * v * (1.0f + erff(v * 0.70710678118654752f));
                C[(size_t)row * N + col] = v;
            }
        }
    }
}

// ---------------- attention: scores + softmax + attn-out + PV ----------------
// one block per (b, h, qi); 256 threads
__global__ __launch_bounds__(256) void attn_kernel(
    const float* __restrict__ q, const float* __restrict__ k, const float* __restrict__ v,
    const int* __restrict__ mask, float* __restrict__ attn_out, float* __restrict__ o)
{
    int bid = blockIdx.x;
    int qi = bid & (SEQ - 1);
    int h = (bid >> 9) & (NHEAD - 1);
    int b = bid >> 12;
    int t = threadIdx.x;

    __shared__ float sq[DK];
    __shared__ float sp[SEQ];
    __shared__ float red[256];

    const float* qrow = q + ((size_t)(b * SEQ + qi) * D_MODEL + h * DK);
    if (t < DK) sq[t] = qrow[t];
    __syncthreads();

    float sc[2];
#pragma unroll
    for (int rep = 0; rep < 2; rep++) {
        int j = t + rep * 256;
        const float4* krow = (const float4*)(k + ((size_t)(b * SEQ + j) * D_MODEL + h * DK));
        float acc = 0.f;
#pragma unroll
        for (int d4 = 0; d4 < 32; d4++) {
            float4 kv = krow[d4];
            float4 qv = *(const float4*)&sq[d4 * 4];   // LDS broadcast
            acc += kv.x * qv.x + kv.y * qv.y + kv.z * qv.z + kv.w * qv.w;
        }
        acc *= 0.08838834764831845f;   // 1/sqrt(128)
        if (mask[b * SEQ + j] == 0) acc = -1e9f;
        sc[rep] = acc;
    }

    float m = block_reduce_max256(fmaxf(sc[0], sc[1]), red);
    float e0 = expf(sc[0] - m), e1 = expf(sc[1] - m);
    float s = block_reduce_sum256(e0 + e1, red);
    float inv = 1.0f / s;
    e0 *= inv; e1 *= inv;
    sp[t] = e0; sp[t + 256] = e1;
    __syncthreads();

    float* arow = attn_out + ((size_t)((b * NHEAD + h) * SEQ + qi)) * SEQ;
    arow[t] = e0; arow[t + 256] = e1;

    // PV: thread t -> d = t&127, j-half = t>>7 ; v reads d-coalesced
    int d = t & 127, jh = t >> 7;
    const float* vb = v + (size_t)(b * SEQ + jh * 256) * D_MODEL + h * DK + d;
    float acc = 0.f;
#pragma unroll 8
    for (int j = 0; j < 256; j++)
        acc += sp[jh * 256 + j] * vb[(size_t)j * D_MODEL];
    red[t] = acc;
    __syncthreads();
    if (t < 128)
        o[(size_t)(b * SEQ + qi) * D_MODEL + h * DK + t] = red[t] + red[t + 128];
}

// ---------------- residual + LayerNorm (x = LN(x + r)) ----------------
__global__ __launch_bounds__(256) void ln_residual_kernel(
    float* __restrict__ x, const float* __restrict__ r,
    const float* __restrict__ g, const float* __restrict__ beta)
{
    int row = blockIdx.x;
    int t = threadIdx.x;
    __shared__ float red[256];
    float* xr = x + (size_t)row * D_MODEL;
    const float* rr = r + (size_t)row * D_MODEL;
    float v[4];
    float sum = 0.f;
#pragma unroll
    for (int i = 0; i < 4; i++) { v[i] = xr[t + i * 256] + rr[t + i * 256]; sum += v[i]; }
    float mean = block_reduce_sum256(sum, red) * (1.0f / D_MODEL);
    float sq = 0.f;
#pragma unroll
    for (int i = 0; i < 4; i++) { float dd = v[i] - mean; sq += dd * dd; }
    float var = block_reduce_sum256(sq, red) * (1.0f / D_MODEL);
    float rinv = rsqrtf(var + 1e-5f);
#pragma unroll
    for (int i = 0; i < 4; i++) {
        int d = t + i * 256;
        xr[d] = (v[i] - mean) * rinv * g[d] + beta[d];
    }
}

// ---------------- masked mean pooling ----------------
__global__ __launch_bounds__(256) void pool_kernel(
    const float* __restrict__ x, const int* __restrict__ mask,
    float* __restrict__ pooled_ws, float* __restrict__ pooled_out)
{
    int b = blockIdx.x;
    int t = threadIdx.x;
    __shared__ float mf[SEQ];
    __shared__ float red[256];
    float pms = 0.f;
    for (int s = t; s < SEQ; s += 256) { float m = (float)mask[b * SEQ + s]; mf[s] = m; pms += m; }
    float msum = block_reduce_sum256(pms, red);
    float minv = 1.0f / msum;
#pragma unroll
    for (int i = 0; i < 4; i++) {
        int d = t + i * 256;
        float acc = 0.f;
        for (int s = 0; s < SEQ; s++)
            acc += x[(size_t)(b * SEQ + s) * D_MODEL + d] * mf[s];
        float pv = acc * minv;
        pooled_ws[b * D_MODEL + d] = pv;
        pooled_out[b * D_MODEL + d] = pv;
    }
}

// ---------------- classifier heads ----------------
__global__ __launch_bounds__(256) void cls_kernel(
    const float* __restrict__ pooled,
    const float* __restrict__ w_cls, const float* __restrict__ b_cls,
    const float* __restrict__ w_int, const float* __restrict__ b_int,
    float* __restrict__ out_sent, float* __restrict__ out_int)
{
    int b = blockIdx.x;
    int t = threadIdx.x;
    __shared__ float red[256];
    float a0 = 0.f, a1 = 0.f, a2 = 0.f, a3 = 0.f;
    for (int d = t; d < D_MODEL; d += 256) {
        float p = pooled[b * D_MODEL + d];
        a0 += p * w_cls[d * 3 + 0];
        a1 += p * w_cls[d * 3 + 1];
        a2 += p * w_cls[d * 3 + 2];
        a3 += p * w_int[d];
    }
    float l0 = block_reduce_sum256(a0, red);
    float l1 = block_reduce_sum256(a1, red);
    float l2 = block_reduce_sum256(a2, red);
    float li = block_reduce_sum256(a3, red);
    if (t == 0) {
        l0 += b_cls[0]; l1 += b_cls[1]; l2 += b_cls[2];
        float m = fmaxf(l0, fmaxf(l1, l2));
        float e0 = expf(l0 - m), e1 = expf(l1 - m), e2 = expf(l2 - m);
        float s = e0 + e1 + e2;
        out_sent[b * 3 + 0] = e0 / s;
        out_sent[b * 3 + 1] = e1 / s;
        out_sent[b * 3 + 2] = e2 / s;
        out_int[b] = 1.0f / (1.0f + expf(-(li + b_int[0])));
    }
}

// ---------------- host launch ----------------
extern "C" void kernel_launch(void* const* d_in, const int* in_sizes, int n_in,
                              void* d_out, int out_size, void* d_ws, size_t ws_size,
                              hipStream_t stream)
{
    const int*   input_ids = (const int*)d_in[0];
    const int*   attn_mask = (const int*)d_in[1];
    const float* emb   = (const float*)d_in[2];
    const float* wq    = (const float*)d_in[3];
    const float* bq    = (const float*)d_in[4];
    const float* wk    = (const float*)d_in[5];
    const float* bk    = (const float*)d_in[6];
    const float* wv    = (const float*)d_in[7];
    const float* bv    = (const float*)d_in[8];
    const float* wo    = (const float*)d_in[9];
    const float* bo    = (const float*)d_in[10];
    const float* w1    = (const float*)d_in[11];
    const float* b1    = (const float*)d_in[12];
    const float* w2    = (const float*)d_in[13];
    const float* b2    = (const float*)d_in[14];
    const float* ln1_g = (const float*)d_in[15];
    const float* ln1_b = (const float*)d_in[16];
    const float* ln2_g = (const float*)d_in[17];
    const float* ln2_b = (const float*)d_in[18];
    const float* w_cls = (const float*)d_in[19];
    const float* b_cls = (const float*)d_in[20];
    const float* w_int = (const float*)d_in[21];
    const float* b_int = (const float*)d_in[22];

    float* out = (float*)d_out;
    // output concat layout (floats): (sentiment, intensity, x, pooled, attn x4)
    const size_t OFF_SENT = 0;                                     // [8,3]
    const size_t OFF_INT  = 24;                                    // [8,1]
    const size_t OFF_X    = 32;                                    // [8,512,1024]
    const size_t OFF_POOL = OFF_X + (size_t)NTOK * D_MODEL;
    const size_t OFF_ATTN = OFF_POOL + (size_t)BATCH * D_MODEL;
    const size_t ATTN_SZ  = (size_t)BATCH * NHEAD * SEQ * SEQ;

    // workspace layout (float units)
    float* ws = (float*)d_ws;
    const size_t XT = (size_t)NTOK * D_MODEL;    // 4 M floats
    const size_t M1 = (size_t)D_MODEL * D_MODEL; // 1 M elems
    float* x    = ws;                 // XT
    float* q    = ws + XT;            // XT (also reused as FF2 output)
    float* kbuf = ws + 2 * XT;        // XT
    float* vbuf = ws + 3 * XT;        // XT
    float* ff   = ws + 4 * XT;        // 4*XT floats (NTOK x FF_DIM)
    float* obuf = ff;                 // alias: dead before ff1 GEMM writes ff
    float* tmp1 = ff + XT;            // alias: dead before ff1 GEMM writes ff
    unsigned short* wt = (unsigned short*)(ws + 8 * XT);  // 12*M1 bf16 = 6*M1 floats
    float* pool = (float*)(wt + 12 * M1);

    size_t need = ((size_t)(8 * XT) + 6 * M1 + (size_t)BATCH * D_MODEL) * sizeof(float);
    if (ws_size < need) {
        fprintf(stderr, "kernel_launch: ws_size %zu < needed %zu\n", ws_size, need);
        return;
    }

    embed_pe_kernel<<<NTOK, 256, 0, stream>>>(input_ids, emb, x);

    unsigned short* wtq = wt;
    unsigned short* wtk = wt + 1 * M1;
    unsigned short* wtv = wt + 2 * M1;
    unsigned short* wto = wt + 3 * M1;
    unsigned short* wt1 = wt + 4 * M1;   // [FF][D] = 4*M1
    unsigned short* wt2 = wt + 8 * M1;   // [D][FF] = 4*M1

    for (int l = 0; l < NLAYER; l++) {
        const float* wq_l = wq + (size_t)l * M1;
        const float* wk_l = wk + (size_t)l * M1;
        const float* wv_l = wv + (size_t)l * M1;
        const float* wo_l = wo + (size_t)l * M1;
        const float* w1_l = w1 + (size_t)l * D_MODEL * FF_DIM;
        const float* w2_l = w2 + (size_t)l * FF_DIM * D_MODEL;

        dim3 gT_DD(D_MODEL / 32, D_MODEL / 32);
        transpose_bf16_kernel<<<gT_DD, 256, 0, stream>>>(wq_l, wtq, D_MODEL, D_MODEL);
        transpose_bf16_kernel<<<gT_DD, 256, 0, stream>>>(wk_l, wtk, D_MODEL, D_MODEL);
        transpose_bf16_kernel<<<gT_DD, 256, 0, stream>>>(wv_l, wtv, D_MODEL, D_MODEL);
        transpose_bf16_kernel<<<gT_DD, 256, 0, stream>>>(wo_l, wto, D_MODEL, D_MODEL);
        dim3 gT_1(FF_DIM / 32, D_MODEL / 32);
        transpose_bf16_kernel<<<gT_1, 256, 0, stream>>>(w1_l, wt1, D_MODEL, FF_DIM);
        dim3 gT_2(D_MODEL / 32, FF_DIM / 32);
        transpose_bf16_kernel<<<gT_2, 256, 0, stream>>>(w2_l, wt2, FF_DIM, D_MODEL);

        dim3 gDD(D_MODEL / 128, NTOK / 128);   // (8, 32)
        gemm_mfma_kernel<<<gDD, 256, 0, stream>>>(x, wtq, bq + l * D_MODEL, q,    NTOK, D_MODEL, D_MODEL, 0);
        gemm_mfma_kernel<<<gDD, 256, 0, stream>>>(x, wtk, bk + l * D_MODEL, kbuf, NTOK, D_MODEL, D_MODEL, 0);
        gemm_mfma_kernel<<<gDD, 256, 0, stream>>>(x, wtv, bv + l * D_MODEL, vbuf, NTOK, D_MODEL, D_MODEL, 0);

        attn_kernel<<<BATCH * NHEAD * SEQ, 256, 0, stream>>>(
            q, kbuf, vbuf, attn_mask, out + OFF_ATTN + (size_t)l * ATTN_SZ, obuf);

        gemm_mfma_kernel<<<gDD, 256, 0, stream>>>(obuf, wto, bo + l * D_MODEL, tmp1, NTOK, D_MODEL, D_MODEL, 0);
        ln_residual_kernel<<<NTOK, 256, 0, stream>>>(x, tmp1, ln1_g + l * D_MODEL, ln1_b + l * D_MODEL);

        dim3 gFF1(FF_DIM / 128, NTOK / 128);   // (32, 32)
        gemm_mfma_kernel<<<gFF1, 256, 0, stream>>>(x, wt1, b1 + l * FF_DIM, ff, NTOK, FF_DIM, D_MODEL, 1);
        dim3 gFF2(D_MODEL / 128, NTOK / 128);
        gemm_mfma_kernel<<<gFF2, 256, 0, stream>>>(ff, wt2, b2 + l * D_MODEL, q, NTOK, D_MODEL, FF_DIM, 0);
        ln_residual_kernel<<<NTOK, 256, 0, stream>>>(x, q, ln2_g + l * D_MODEL, ln2_b + l * D_MODEL);
    }

    hipMemcpyAsync(out + OFF_X, x, XT * sizeof(float), hipMemcpyDeviceToDevice, stream);

    pool_kernel<<<BATCH, 256, 0, stream>>>(x, attn_mask, pool, out + OFF_POOL);
    cls_kernel<<<BATCH, 256, 0, stream>>>(pool, w_cls, b_cls, w_int, b_int,
                                          out + OFF_SENT, out + OFF_INT);
}